// Round 7
// baseline (540.160 us; speedup 1.0000x reference)
//
#include <hip/hip_runtime.h>
#include <math.h>

#define S_ 512
#define B_ 64
#define C_ 1024
#define T_ 128
#define V_ 10
#define LN_EPS 1e-5f

// DPP reduce-add helper: x += x permuted by CTRL (all lanes active).
// CTRL: 0xB1 = quad_perm[1,0,3,2] (xor1), 0x4E = quad_perm[2,3,0,1] (xor2),
//       0x141 = row_half_mirror (xor4 within 8), 0x128 = row_ror:8 (xor8
//       within the 16-lane row).
#define DPP_ADD(x, ctrl)                                                     \
    ((x) + __int_as_float(__builtin_amdgcn_update_dpp(                       \
               0, __float_as_int(x), (ctrl), 0xf, 0xf, true)))

// ---------- Phase 1a: per (t,b): softmax(values@Wd.T+bd), sigmoid(values@Wr[1]+br[1])
__global__ __launch_bounds__(256) void k_dirs(const float* __restrict__ values,
                                              const float* __restrict__ Wd,
                                              const float* __restrict__ bd,
                                              const float* __restrict__ Wr,
                                              const float* __restrict__ br,
                                              float* __restrict__ dtr) {
    int wid  = (blockIdx.x << 2) + (threadIdx.x >> 6);   // 0..32767 = t*64+b
    int lane = threadIdx.x & 63;
    const float4* v4  = (const float4*)(values + (size_t)wid * C_);
    const float4* wd4 = (const float4*)Wd;
    const float4* wr4 = (const float4*)Wr;
    float a0 = 0.f, a1 = 0.f, a2 = 0.f, a3 = 0.f;
#pragma unroll
    for (int k = 0; k < 4; k++) {
        int i = (k << 6) + lane;           // float4 index within 256
        float4 v  = v4[i];
        float4 w0 = wd4[i];
        float4 w1 = wd4[256 + i];
        float4 w2 = wd4[512 + i];
        float4 w3 = wr4[256 + i];          // Wr row 1
        a0 = fmaf(v.x, w0.x, fmaf(v.y, w0.y, fmaf(v.z, w0.z, fmaf(v.w, w0.w, a0))));
        a1 = fmaf(v.x, w1.x, fmaf(v.y, w1.y, fmaf(v.z, w1.z, fmaf(v.w, w1.w, a1))));
        a2 = fmaf(v.x, w2.x, fmaf(v.y, w2.y, fmaf(v.z, w2.z, fmaf(v.w, w2.w, a2))));
        a3 = fmaf(v.x, w3.x, fmaf(v.y, w3.y, fmaf(v.z, w3.z, fmaf(v.w, w3.w, a3))));
    }
#pragma unroll
    for (int m = 1; m < 64; m <<= 1) {
        a0 += __shfl_xor(a0, m, 64);
        a1 += __shfl_xor(a1, m, 64);
        a2 += __shfl_xor(a2, m, 64);
        a3 += __shfl_xor(a3, m, 64);
    }
    if (lane == 0) {
        float l0 = a0 + bd[0], l1 = a1 + bd[1], l2 = a2 + bd[2];
        float mx = fmaxf(fmaxf(l0, l1), l2);
        float e0 = __expf(l0 - mx), e1 = __expf(l1 - mx), e2 = __expf(l2 - mx);
        float inv = 1.f / (e0 + e1 + e2);
        float r = 1.f / (1.f + __expf(-(a3 + br[1])));
        ((float4*)dtr)[wid] = make_float4(e0 * inv, e1 * inv, e2 * inv, r);
    }
}

// ---------- Phase 1b: evolve pos per batch; store pos_t (pre-update) for all t.
__global__ __launch_bounds__(64) void k_pos(const float* __restrict__ dtr,
                                            float* __restrict__ pos_all) {
    int b = blockIdx.x;
    int lane = threadIdx.x;
    const float4* dtr4 = (const float4*)dtr;
    float4 dreg[8];
#pragma unroll
    for (int k = 0; k < 8; k++)
        dreg[k] = dtr4[(((size_t)(k << 6) + lane) << 6) + b];   // t = k*64+lane
    float p0 = (lane == 0) ? 1.f : 0.f;
    float p1 = 0.f;
    float* outp = pos_all + ((size_t)b << 7) + lane;
    int up = (lane + 1) & 63, dw = (lane + 63) & 63;
#pragma unroll
    for (int k = 0; k < 8; k++) {
#pragma unroll 4
        for (int tt = 0; tt < 64; tt++) {
            int t = (k << 6) + tt;
            float d0 = __shfl(dreg[k].x, tt, 64);
            float d1 = __shfl(dreg[k].y, tt, 64);
            float d2 = __shfl(dreg[k].z, tt, 64);
            outp[(size_t)t * (B_ * T_)]      = p0;   // pos_t before update
            outp[(size_t)t * (B_ * T_) + 64] = p1;
            float s0n = __shfl(p0, up, 64), s1n = __shfl(p1, up, 64);
            float s0p = __shfl(p0, dw, 64), s1p = __shfl(p1, dw, 64);
            float up0 = (lane == 63) ? s1n : s0n;   // pos[(l+1)%128], l=lane
            float dn0 = (lane == 0)  ? s1p : s0p;   // pos[(l-1)%128]
            float up1 = (lane == 63) ? s0n : s1n;   // l=lane+64
            float dn1 = (lane == 0)  ? s0p : s1p;
            p0 = fmaf(up0, d0, fmaf(p0, d1, dn0 * d2));
            p1 = fmaf(up1, d0, fmaf(p1, d1, dn1 * d2));
        }
    }
}

// ---------- Phase 2: the scan, 4 waves/SIMD occupancy remap.
// Thread = 8 l x 4 c. Lanes: g = lane&15 (l in [8g, 8g+8)), cl = lane>>4.
// 16 l-groups -> reduce = 4 DPP rounds (xor1/2/4/8 within the 16-lane row),
// pure VALU, no LDS pipe. Total waves double vs cpt=4/8-group mapping ->
// 1024 blocks = 4 blocks/CU = 4 waves/SIMD, same per-CU LDS pos traffic
// (16 waves x 2 ds_read_b128 == 8 waves x 4).
// pos LDS: store slot p(f) = (f&1)*16 + (f>>1); thread g reads slots g and
// 16+g -> two reads of 16 consecutive slots, 2-way bank aliasing (free).
// v LDS: block's 64 c = 16 float4, identity; read slot (wv<<2)+cl, broadcast.
// T14 staging: global->reg at chunk start, ds_write after compute, 1 barrier
// per 8 steps, double-buffered.
__global__ __launch_bounds__(256, 4) void k_scan(const float* __restrict__ values,
                                                 const float* __restrict__ dtr,
                                                 const float* __restrict__ pos_all,
                                                 float* __restrict__ tape_out) {
    const int b    = blockIdx.x >> 4;
    const int cblk = blockIdx.x & 15;
    const int tid  = threadIdx.x;
    const int lane = tid & 63;
    const int wv   = tid >> 6;            // wave in block, 0..3
    const int g    = lane & 15;           // l-group (8 l's: [8g, 8g+8))
    const int cl   = lane >> 4;           // c-slot in wave, 0..3
    const int c0   = (cblk << 6) + (wv << 4) + (cl << 2);   // 4 consecutive c

    __shared__ float4 pos_s[2][8][32];    // [buf][t][permuted float4 of 128 l]
    __shared__ float4 v_s[2][8][16];      // [buf][t][float4 of block's 64 c]
    __shared__ float  rw_s[2][8];

    float tape[8][4];
#pragma unroll
    for (int k = 0; k < 8; k++)
#pragma unroll
        for (int c = 0; c < 4; c++) tape[k][c] = 0.f;

    // staging roles
    const int ptl  = tid >> 5;            // 0..7 (t within chunk), pos
    const int pi   = tid & 31;            // source float4 index
    const int pdst = ((pi & 1) << 4) + (pi >> 1);   // interleave permutation
    const int vtl  = (tid >> 4) & 7;      // t within chunk, v (tid<128)
    const int vi   = tid & 15;            // v float4 index within block's 64 c
    const float4* pos4 = (const float4*)pos_all;
    const float4* val4 = (const float4*)values;
    const size_t  vsrc = (size_t)b * (C_ / 4) + (cblk << 4) + vi;

    // ---- prologue: stage chunk 0
    {
        pos_s[0][ptl][pdst] = pos4[((size_t)ptl * B_ + b) * (T_ / 4) + pi];
        if (tid < 128) v_s[0][vtl][vi] = val4[(size_t)vtl * (B_ * C_ / 4) + vsrc];
        if (tid < 8)   rw_s[0][tid] = dtr[(((size_t)tid * B_ + b) << 2) + 3];
    }
    __syncthreads();

    int cur = 0;
    for (int ch = 0; ch < S_ / 8; ch++) {
        // ---- prefetch chunk ch+1 into regs (clamped re-read on last chunk)
        const int t0n = (ch + 1 < S_ / 8) ? ((ch + 1) << 3) : 0;
        float4 pfp = pos4[((size_t)(t0n + ptl) * B_ + b) * (T_ / 4) + pi];
        float4 pfv = (tid < 128)
                         ? val4[(size_t)(t0n + vtl) * (B_ * C_ / 4) + vsrc]
                         : make_float4(0.f, 0.f, 0.f, 0.f);
        float  pfr = (tid < 8) ? dtr[(((size_t)(t0n + tid) * B_ + b) << 2) + 3] : 0.f;

        // ---- compute 8 steps from buf cur
#pragma unroll
        for (int ts = 0; ts < 8; ts++) {
            float4 pj0 = pos_s[cur][ts][g];          // l = 8g .. 8g+3
            float4 pj1 = pos_s[cur][ts][16 + g];     // l = 8g+4 .. 8g+7
            float4 vv  = v_s[cur][ts][(wv << 2) + cl];
            float  rw  = rw_s[cur][ts];
            float pk[8];
            pk[0] = pj0.x; pk[1] = pj0.y; pk[2] = pj0.z; pk[3] = pj0.w;
            pk[4] = pj1.x; pk[5] = pj1.y; pk[6] = pj1.z; pk[7] = pj1.w;

            float ov[4] = {0.f, 0.f, 0.f, 0.f};
#pragma unroll
            for (int k = 0; k < 8; k++) {
                ov[0] = fmaf(tape[k][0], pk[k], ov[0]);
                ov[1] = fmaf(tape[k][1], pk[k], ov[1]);
                ov[2] = fmaf(tape[k][2], pk[k], ov[2]);
                ov[3] = fmaf(tape[k][3], pk[k], ov[3]);
            }
            // DPP reduce over the 16 l-groups (lane bits 0..3), pure VALU
#pragma unroll
            for (int c = 0; c < 4; c++) {
                ov[c] = DPP_ADD(ov[c], 0xB1);    // += lane^1
                ov[c] = DPP_ADD(ov[c], 0x4E);    // += lane^2
                ov[c] = DPP_ADD(ov[c], 0x141);   // += lane^4 (half-mirror)
                ov[c] = DPP_ADD(ov[c], 0x128);   // += lane^8 (row_ror:8)
            }
            float de[4];
            de[0] = (vv.x - ov[0]) * rw;
            de[1] = (vv.y - ov[1]) * rw;
            de[2] = (vv.z - ov[2]) * rw;
            de[3] = (vv.w - ov[3]) * rw;
#pragma unroll
            for (int k = 0; k < 8; k++) {
                tape[k][0] = fmaf(pk[k], de[0], tape[k][0]);
                tape[k][1] = fmaf(pk[k], de[1], tape[k][1]);
                tape[k][2] = fmaf(pk[k], de[2], tape[k][2]);
                tape[k][3] = fmaf(pk[k], de[3], tape[k][3]);
            }
        }
        // ---- land prefetched chunk into the other buffer
        int nxt = cur ^ 1;
        pos_s[nxt][ptl][pdst] = pfp;
        if (tid < 128) v_s[nxt][vtl][vi] = pfv;
        if (tid < 8)   rw_s[nxt][tid] = pfr;
        __syncthreads();
        cur = nxt;
    }

    // writeout: layout [l][b][c]; this lane owns l = 8g + k, c = c0..c0+3
#pragma unroll
    for (int k = 0; k < 8; k++) {
        int l = (g << 3) + k;
        *(float4*)(tape_out + ((size_t)l * B_ + b) * C_ + c0) =
            make_float4(tape[k][0], tape[k][1], tape[k][2], tape[k][3]);
    }
}

// ---------- Phase 3: LayerNorm over C + projection to V=10. one wave per (l,b).
__global__ __launch_bounds__(256) void k_out(const float* __restrict__ tape,
                                             const float* __restrict__ ln_g,
                                             const float* __restrict__ ln_b,
                                             const float* __restrict__ Wo,
                                             const float* __restrict__ bo,
                                             float* __restrict__ out) {
    int wid  = (blockIdx.x << 2) + (threadIdx.x >> 6);   // 0..8191 = l*64+b
    int lane = threadIdx.x & 63;
    const float* tr = tape + (size_t)wid * C_;
    float x[16];
    float s = 0.f, s2 = 0.f;
#pragma unroll
    for (int k = 0; k < 16; k++) {
        x[k] = tr[(k << 6) + lane];
        s += x[k];
        s2 = fmaf(x[k], x[k], s2);
    }
#pragma unroll
    for (int m = 1; m < 64; m <<= 1) {
        s  += __shfl_xor(s,  m, 64);
        s2 += __shfl_xor(s2, m, 64);
    }
    float mu = s * (1.f / C_);
    float var = s2 * (1.f / C_) - mu * mu;
    float rstd = rsqrtf(var + LN_EPS);
    float acc[V_];
#pragma unroll
    for (int v = 0; v < V_; v++) acc[v] = 0.f;
#pragma unroll
    for (int k = 0; k < 16; k++) {
        int cc = (k << 6) + lane;
        float h = fmaf((x[k] - mu) * rstd, ln_g[cc], ln_b[cc]);
#pragma unroll
        for (int v = 0; v < V_; v++) acc[v] = fmaf(h, Wo[v * C_ + cc], acc[v]);
    }
#pragma unroll
    for (int v = 0; v < V_; v++) {
#pragma unroll
        for (int m = 1; m < 64; m <<= 1) acc[v] += __shfl_xor(acc[v], m, 64);
    }
    if (lane == 0) {
#pragma unroll
        for (int v = 0; v < V_; v++) out[(size_t)wid * V_ + v] = acc[v] + bo[v];
    }
}

extern "C" void kernel_launch(void* const* d_in, const int* in_sizes, int n_in,
                              void* d_out, int out_size, void* d_ws, size_t ws_size,
                              hipStream_t stream) {
    const float* values = (const float*)d_in[0];
    const float* Wd     = (const float*)d_in[1];
    const float* bd     = (const float*)d_in[2];
    const float* Wr     = (const float*)d_in[3];
    const float* br     = (const float*)d_in[4];
    const float* ln_g   = (const float*)d_in[5];
    const float* ln_b   = (const float*)d_in[6];
    const float* Wo     = (const float*)d_in[7];
    const float* bo     = (const float*)d_in[8];
    float* out = (float*)d_out;

    // workspace layout (floats): dtr [512*64*4] | pos_all [512*64*128] | tape [128*64*1024]
    float* dtr     = (float*)d_ws;
    float* pos_all = dtr + (size_t)S_ * B_ * 4;
    float* tape    = pos_all + (size_t)S_ * B_ * T_;

    k_dirs<<<dim3((S_ * B_) / 4), dim3(256), 0, stream>>>(values, Wd, bd, Wr, br, dtr);
    k_pos <<<dim3(B_),            dim3(64),  0, stream>>>(dtr, pos_all);
    k_scan<<<dim3(B_ * 16),       dim3(256), 0, stream>>>(values, dtr, pos_all, tape);
    k_out <<<dim3((T_ * B_) / 4), dim3(256), 0, stream>>>(tape, ln_g, ln_b, Wo, bo, out);
}

// Round 8
// 502.588 us; speedup vs baseline: 1.0748x; 1.0748x over previous
//
#include <hip/hip_runtime.h>
#include <math.h>

#define S_ 512
#define B_ 64
#define C_ 1024
#define T_ 128
#define V_ 10
#define LN_EPS 1e-5f

// DPP reduce-add helper: x += x permuted by CTRL (all lanes active).
// CTRL: 0xB1 = quad_perm[1,0,3,2] (xor1), 0x4E = quad_perm[2,3,0,1] (xor2),
//       0x141 = row_half_mirror (xor4 within 8 lanes).
#define DPP_ADD(x, ctrl)                                                     \
    ((x) + __int_as_float(__builtin_amdgcn_update_dpp(                       \
               0, __float_as_int(x), (ctrl), 0xf, 0xf, true)))

// ---------- Phase 1a: per (t,b): softmax(values@Wd.T+bd), sigmoid(values@Wr[1]+br[1])
__global__ __launch_bounds__(256) void k_dirs(const float* __restrict__ values,
                                              const float* __restrict__ Wd,
                                              const float* __restrict__ bd,
                                              const float* __restrict__ Wr,
                                              const float* __restrict__ br,
                                              float* __restrict__ dtr) {
    int wid  = (blockIdx.x << 2) + (threadIdx.x >> 6);   // 0..32767 = t*64+b
    int lane = threadIdx.x & 63;
    const float4* v4  = (const float4*)(values + (size_t)wid * C_);
    const float4* wd4 = (const float4*)Wd;
    const float4* wr4 = (const float4*)Wr;
    float a0 = 0.f, a1 = 0.f, a2 = 0.f, a3 = 0.f;
#pragma unroll
    for (int k = 0; k < 4; k++) {
        int i = (k << 6) + lane;           // float4 index within 256
        float4 v  = v4[i];
        float4 w0 = wd4[i];
        float4 w1 = wd4[256 + i];
        float4 w2 = wd4[512 + i];
        float4 w3 = wr4[256 + i];          // Wr row 1
        a0 = fmaf(v.x, w0.x, fmaf(v.y, w0.y, fmaf(v.z, w0.z, fmaf(v.w, w0.w, a0))));
        a1 = fmaf(v.x, w1.x, fmaf(v.y, w1.y, fmaf(v.z, w1.z, fmaf(v.w, w1.w, a1))));
        a2 = fmaf(v.x, w2.x, fmaf(v.y, w2.y, fmaf(v.z, w2.z, fmaf(v.w, w2.w, a2))));
        a3 = fmaf(v.x, w3.x, fmaf(v.y, w3.y, fmaf(v.z, w3.z, fmaf(v.w, w3.w, a3))));
    }
#pragma unroll
    for (int m = 1; m < 64; m <<= 1) {
        a0 += __shfl_xor(a0, m, 64);
        a1 += __shfl_xor(a1, m, 64);
        a2 += __shfl_xor(a2, m, 64);
        a3 += __shfl_xor(a3, m, 64);
    }
    if (lane == 0) {
        float l0 = a0 + bd[0], l1 = a1 + bd[1], l2 = a2 + bd[2];
        float mx = fmaxf(fmaxf(l0, l1), l2);
        float e0 = __expf(l0 - mx), e1 = __expf(l1 - mx), e2 = __expf(l2 - mx);
        float inv = 1.f / (e0 + e1 + e2);
        float r = 1.f / (1.f + __expf(-(a3 + br[1])));
        ((float4*)dtr)[wid] = make_float4(e0 * inv, e1 * inv, e2 * inv, r);
    }
}

// ---------- Phase 1b: evolve pos per batch; store pos_t (pre-update) for all t.
__global__ __launch_bounds__(64) void k_pos(const float* __restrict__ dtr,
                                            float* __restrict__ pos_all) {
    int b = blockIdx.x;
    int lane = threadIdx.x;
    const float4* dtr4 = (const float4*)dtr;
    float4 dreg[8];
#pragma unroll
    for (int k = 0; k < 8; k++)
        dreg[k] = dtr4[(((size_t)(k << 6) + lane) << 6) + b];   // t = k*64+lane
    float p0 = (lane == 0) ? 1.f : 0.f;
    float p1 = 0.f;
    float* outp = pos_all + ((size_t)b << 7) + lane;
    int up = (lane + 1) & 63, dw = (lane + 63) & 63;
#pragma unroll
    for (int k = 0; k < 8; k++) {
#pragma unroll 4
        for (int tt = 0; tt < 64; tt++) {
            int t = (k << 6) + tt;
            float d0 = __shfl(dreg[k].x, tt, 64);
            float d1 = __shfl(dreg[k].y, tt, 64);
            float d2 = __shfl(dreg[k].z, tt, 64);
            outp[(size_t)t * (B_ * T_)]      = p0;   // pos_t before update
            outp[(size_t)t * (B_ * T_) + 64] = p1;
            float s0n = __shfl(p0, up, 64), s1n = __shfl(p1, up, 64);
            float s0p = __shfl(p0, dw, 64), s1p = __shfl(p1, dw, 64);
            float up0 = (lane == 63) ? s1n : s0n;   // pos[(l+1)%128], l=lane
            float dn0 = (lane == 0)  ? s1p : s0p;   // pos[(l-1)%128]
            float up1 = (lane == 63) ? s0n : s1n;   // l=lane+64
            float dn1 = (lane == 0)  ? s0p : s1p;
            p0 = fmaf(up0, d0, fmaf(p0, d1, dn0 * d2));
            p1 = fmaf(up1, d0, fmaf(p1, d1, dn1 * d2));
        }
    }
}

// ---------- Phase 2: the scan, round-6 skeleton + K=2 lookahead.
// Per PAIR of steps: one fused pass computes A1 = tape.p1, A2 = tape.p2,
// G = p1.p2 off the OLD tape (independent chains), one DPP-reduce phase
// (9 values), then d1 = rw1(v1-A1), d2 = rw2(v2-A2-G*d1) (scalar fixup),
// and a rank-2 tape update. Halves the serial per-step dependency chain
// (dot->reduce->delta->update) at +6% issue.
// Lanes: g = lane&7 (16 l's: [16g,16g+16)), cl = lane>>3 (4 c's).
// pos LDS slot p(pi) = (pi&3)*8 + (pi>>2); read [ts][j*8+g] -> all 32 banks.
// T14 staging: global->reg at chunk start, ds_write after compute, 1 barrier
// per 8 steps, double-buffered. Grid: 512 blocks = 2 waves/SIMD.
__global__ __launch_bounds__(256, 2) void k_scan(const float* __restrict__ values,
                                                 const float* __restrict__ dtr,
                                                 const float* __restrict__ pos_all,
                                                 float* __restrict__ tape_out) {
    const int b    = blockIdx.x >> 3;
    const int cblk = blockIdx.x & 7;
    const int tid  = threadIdx.x;
    const int lane = tid & 63;
    const int wv   = tid >> 6;            // wave in block, 0..3
    const int g    = lane & 7;            // l-group
    const int cl   = lane >> 3;           // c-slot in wave, 0..7
    const int c0   = (cblk << 7) + (wv << 5) + (cl << 2);   // 4 consecutive c

    __shared__ float4 pos_s[2][8][32];    // [buf][t][permuted float4 of 128 l]
    __shared__ float4 v_s[2][8][32];      // [buf][t][float4 of block's 128 c]
    __shared__ float  rw_s[2][8];

    float tape[16][4];
#pragma unroll
    for (int k = 0; k < 16; k++)
#pragma unroll
        for (int c = 0; c < 4; c++) tape[k][c] = 0.f;

    // staging roles: thread stages one float4 of pos and one of v per chunk
    const int tl   = tid >> 5;            // 0..7 (t within chunk)
    const int pi   = tid & 31;            // source float4 index
    const int pdst = ((pi & 3) << 3) + (pi >> 2);   // interleave permutation
    const float4* pos4 = (const float4*)pos_all;
    const float4* val4 = (const float4*)values;
    const size_t  vsrc = (size_t)b * (C_ / 4) + (cblk << 5) + pi;

    // ---- prologue: stage chunk 0
    {
        pos_s[0][tl][pdst] = pos4[((size_t)tl * B_ + b) * (T_ / 4) + pi];
        v_s[0][tl][pi]     = val4[(size_t)tl * (B_ * C_ / 4) + vsrc];
        if (tid < 8) rw_s[0][tid] = dtr[(((size_t)tid * B_ + b) << 2) + 3];
    }
    __syncthreads();

    int cur = 0;
    for (int ch = 0; ch < S_ / 8; ch++) {
        // ---- prefetch chunk ch+1 into regs (clamped re-read on last chunk)
        const int t0n = (ch + 1 < S_ / 8) ? ((ch + 1) << 3) : 0;
        float4 pfp = pos4[((size_t)(t0n + tl) * B_ + b) * (T_ / 4) + pi];
        float4 pfv = val4[(size_t)(t0n + tl) * (B_ * C_ / 4) + vsrc];
        float  pfr = (tid < 8) ? dtr[(((size_t)(t0n + tid) * B_ + b) << 2) + 3] : 0.f;

        // ---- compute 8 steps = 4 pairs from buf cur
#pragma unroll
        for (int tp = 0; tp < 4; tp++) {
            const int ts0 = tp << 1, ts1 = ts0 + 1;
            float4 qa0 = pos_s[cur][ts0][g];
            float4 qa1 = pos_s[cur][ts0][8 + g];
            float4 qa2 = pos_s[cur][ts0][16 + g];
            float4 qa3 = pos_s[cur][ts0][24 + g];
            float4 qb0 = pos_s[cur][ts1][g];
            float4 qb1 = pos_s[cur][ts1][8 + g];
            float4 qb2 = pos_s[cur][ts1][16 + g];
            float4 qb3 = pos_s[cur][ts1][24 + g];
            float4 v1  = v_s[cur][ts0][(wv << 3) + cl];
            float4 v2  = v_s[cur][ts1][(wv << 3) + cl];
            float  rw1 = rw_s[cur][ts0];
            float  rw2 = rw_s[cur][ts1];
            float pk1[16], pk2[16];
            pk1[0]  = qa0.x; pk1[1]  = qa0.y; pk1[2]  = qa0.z; pk1[3]  = qa0.w;
            pk1[4]  = qa1.x; pk1[5]  = qa1.y; pk1[6]  = qa1.z; pk1[7]  = qa1.w;
            pk1[8]  = qa2.x; pk1[9]  = qa2.y; pk1[10] = qa2.z; pk1[11] = qa2.w;
            pk1[12] = qa3.x; pk1[13] = qa3.y; pk1[14] = qa3.z; pk1[15] = qa3.w;
            pk2[0]  = qb0.x; pk2[1]  = qb0.y; pk2[2]  = qb0.z; pk2[3]  = qb0.w;
            pk2[4]  = qb1.x; pk2[5]  = qb1.y; pk2[6]  = qb1.z; pk2[7]  = qb1.w;
            pk2[8]  = qb2.x; pk2[9]  = qb2.y; pk2[10] = qb2.z; pk2[11] = qb2.w;
            pk2[12] = qb3.x; pk2[13] = qb3.y; pk2[14] = qb3.z; pk2[15] = qb3.w;

            float a1[4] = {0.f, 0.f, 0.f, 0.f};
            float a2[4] = {0.f, 0.f, 0.f, 0.f};
            float gg = 0.f;
#pragma unroll
            for (int k = 0; k < 16; k++) {
                a1[0] = fmaf(tape[k][0], pk1[k], a1[0]);
                a1[1] = fmaf(tape[k][1], pk1[k], a1[1]);
                a1[2] = fmaf(tape[k][2], pk1[k], a1[2]);
                a1[3] = fmaf(tape[k][3], pk1[k], a1[3]);
                a2[0] = fmaf(tape[k][0], pk2[k], a2[0]);
                a2[1] = fmaf(tape[k][1], pk2[k], a2[1]);
                a2[2] = fmaf(tape[k][2], pk2[k], a2[2]);
                a2[3] = fmaf(tape[k][3], pk2[k], a2[3]);
                gg    = fmaf(pk1[k], pk2[k], gg);
            }
            // one DPP-reduce phase over the 8 l-groups (lane bits 0..2)
#pragma unroll
            for (int c = 0; c < 4; c++) {
                a1[c] = DPP_ADD(a1[c], 0xB1);
                a1[c] = DPP_ADD(a1[c], 0x4E);
                a1[c] = DPP_ADD(a1[c], 0x141);
                a2[c] = DPP_ADD(a2[c], 0xB1);
                a2[c] = DPP_ADD(a2[c], 0x4E);
                a2[c] = DPP_ADD(a2[c], 0x141);
            }
            gg = DPP_ADD(gg, 0xB1);
            gg = DPP_ADD(gg, 0x4E);
            gg = DPP_ADD(gg, 0x141);

            float d1[4], d2[4];
            d1[0] = (v1.x - a1[0]) * rw1;
            d1[1] = (v1.y - a1[1]) * rw1;
            d1[2] = (v1.z - a1[2]) * rw1;
            d1[3] = (v1.w - a1[3]) * rw1;
            d2[0] = fmaf(-gg, d1[0], v2.x - a2[0]) * rw2;
            d2[1] = fmaf(-gg, d1[1], v2.y - a2[1]) * rw2;
            d2[2] = fmaf(-gg, d1[2], v2.z - a2[2]) * rw2;
            d2[3] = fmaf(-gg, d1[3], v2.w - a2[3]) * rw2;
            // rank-2 update
#pragma unroll
            for (int k = 0; k < 16; k++) {
                tape[k][0] = fmaf(pk1[k], d1[0], fmaf(pk2[k], d2[0], tape[k][0]));
                tape[k][1] = fmaf(pk1[k], d1[1], fmaf(pk2[k], d2[1], tape[k][1]));
                tape[k][2] = fmaf(pk1[k], d1[2], fmaf(pk2[k], d2[2], tape[k][2]));
                tape[k][3] = fmaf(pk1[k], d1[3], fmaf(pk2[k], d2[3], tape[k][3]));
            }
        }
        // ---- land prefetched chunk into the other buffer
        int nxt = cur ^ 1;
        pos_s[nxt][tl][pdst] = pfp;
        v_s[nxt][tl][pi]     = pfv;
        if (tid < 8) rw_s[nxt][tid] = pfr;
        __syncthreads();
        cur = nxt;
    }

    // writeout: layout [l][b][c]; this lane owns l = 16g + k, c = c0..c0+3
#pragma unroll
    for (int k = 0; k < 16; k++) {
        int l = (g << 4) + k;
        *(float4*)(tape_out + ((size_t)l * B_ + b) * C_ + c0) =
            make_float4(tape[k][0], tape[k][1], tape[k][2], tape[k][3]);
    }
}

// ---------- Phase 3: LayerNorm over C + projection to V=10. one wave per (l,b).
// float4-vectorized loads (52 vs 178 loads/thread).
__global__ __launch_bounds__(256) void k_out(const float* __restrict__ tape,
                                             const float* __restrict__ ln_g,
                                             const float* __restrict__ ln_b,
                                             const float* __restrict__ Wo,
                                             const float* __restrict__ bo,
                                             float* __restrict__ out) {
    int wid  = (blockIdx.x << 2) + (threadIdx.x >> 6);   // 0..8191 = l*64+b
    int lane = threadIdx.x & 63;
    const float4* tr4 = (const float4*)(tape + (size_t)wid * C_);
    float4 x[4];
    float s = 0.f, s2 = 0.f;
#pragma unroll
    for (int j = 0; j < 4; j++) {
        x[j] = tr4[(j << 6) + lane];
        s += (x[j].x + x[j].y) + (x[j].z + x[j].w);
        s2 = fmaf(x[j].x, x[j].x, s2);
        s2 = fmaf(x[j].y, x[j].y, s2);
        s2 = fmaf(x[j].z, x[j].z, s2);
        s2 = fmaf(x[j].w, x[j].w, s2);
    }
#pragma unroll
    for (int m = 1; m < 64; m <<= 1) {
        s  += __shfl_xor(s,  m, 64);
        s2 += __shfl_xor(s2, m, 64);
    }
    float mu = s * (1.f / C_);
    float var = s2 * (1.f / C_) - mu * mu;
    float rstd = rsqrtf(var + LN_EPS);
    float acc[V_];
#pragma unroll
    for (int v = 0; v < V_; v++) acc[v] = 0.f;
    const float4* g4 = (const float4*)ln_g;
    const float4* b4 = (const float4*)ln_b;
    const float4* w4 = (const float4*)Wo;
#pragma unroll
    for (int j = 0; j < 4; j++) {
        int ci = (j << 6) + lane;          // float4 index within C/4
        float4 gg = g4[ci], bb = b4[ci];
        float4 h;
        h.x = fmaf((x[j].x - mu) * rstd, gg.x, bb.x);
        h.y = fmaf((x[j].y - mu) * rstd, gg.y, bb.y);
        h.z = fmaf((x[j].z - mu) * rstd, gg.z, bb.z);
        h.w = fmaf((x[j].w - mu) * rstd, gg.w, bb.w);
#pragma unroll
        for (int v = 0; v < V_; v++) {
            float4 w = w4[v * (C_ / 4) + ci];
            acc[v] = fmaf(h.x, w.x, acc[v]);
            acc[v] = fmaf(h.y, w.y, acc[v]);
            acc[v] = fmaf(h.z, w.z, acc[v]);
            acc[v] = fmaf(h.w, w.w, acc[v]);
        }
    }
#pragma unroll
    for (int v = 0; v < V_; v++) {
#pragma unroll
        for (int m = 1; m < 64; m <<= 1) acc[v] += __shfl_xor(acc[v], m, 64);
    }
    if (lane == 0) {
#pragma unroll
        for (int v = 0; v < V_; v++) out[(size_t)wid * V_ + v] = acc[v] + bo[v];
    }
}

extern "C" void kernel_launch(void* const* d_in, const int* in_sizes, int n_in,
                              void* d_out, int out_size, void* d_ws, size_t ws_size,
                              hipStream_t stream) {
    const float* values = (const float*)d_in[0];
    const float* Wd     = (const float*)d_in[1];
    const float* bd     = (const float*)d_in[2];
    const float* Wr     = (const float*)d_in[3];
    const float* br     = (const float*)d_in[4];
    const float* ln_g   = (const float*)d_in[5];
    const float* ln_b   = (const float*)d_in[6];
    const float* Wo     = (const float*)d_in[7];
    const float* bo     = (const float*)d_in[8];
    float* out = (float*)d_out;

    // workspace layout (floats): dtr [512*64*4] | pos_all [512*64*128] | tape [128*64*1024]
    float* dtr     = (float*)d_ws;
    float* pos_all = dtr + (size_t)S_ * B_ * 4;
    float* tape    = pos_all + (size_t)S_ * B_ * T_;

    k_dirs<<<dim3((S_ * B_) / 4), dim3(256), 0, stream>>>(values, Wd, bd, Wr, br, dtr);
    k_pos <<<dim3(B_),            dim3(64),  0, stream>>>(dtr, pos_all);
    k_scan<<<dim3(B_ * 8),        dim3(256), 0, stream>>>(values, dtr, pos_all, tape);
    k_out <<<dim3((T_ * B_) / 4), dim3(256), 0, stream>>>(tape, ln_g, ln_b, Wo, bo, out);
}

// Round 10
// 480.605 us; speedup vs baseline: 1.1239x; 1.0457x over previous
//
#include <hip/hip_runtime.h>
#include <math.h>

#define S_ 512
#define B_ 64
#define C_ 1024
#define T_ 128
#define V_ 10
#define LN_EPS 1e-5f

// DPP reduce-add helper: x += x permuted by CTRL (all lanes active).
// CTRL: 0xB1 = quad_perm[1,0,3,2] (xor1), 0x4E = quad_perm[2,3,0,1] (xor2),
//       0x141 = row_half_mirror (xor4 within 8 lanes).
#define DPP_ADD(x, ctrl)                                                     \
    ((x) + __int_as_float(__builtin_amdgcn_update_dpp(                       \
               0, __float_as_int(x), (ctrl), 0xf, 0xf, true)))

// ---------- Phase 1a: per (t,b): softmax(values@Wd.T+bd), sigmoid(values@Wr[1]+br[1])
__global__ __launch_bounds__(256) void k_dirs(const float* __restrict__ values,
                                              const float* __restrict__ Wd,
                                              const float* __restrict__ bd,
                                              const float* __restrict__ Wr,
                                              const float* __restrict__ br,
                                              float* __restrict__ dtr) {
    int wid  = (blockIdx.x << 2) + (threadIdx.x >> 6);   // 0..32767 = t*64+b
    int lane = threadIdx.x & 63;
    const float4* v4  = (const float4*)(values + (size_t)wid * C_);
    const float4* wd4 = (const float4*)Wd;
    const float4* wr4 = (const float4*)Wr;
    float a0 = 0.f, a1 = 0.f, a2 = 0.f, a3 = 0.f;
#pragma unroll
    for (int k = 0; k < 4; k++) {
        int i = (k << 6) + lane;           // float4 index within 256
        float4 v  = v4[i];
        float4 w0 = wd4[i];
        float4 w1 = wd4[256 + i];
        float4 w2 = wd4[512 + i];
        float4 w3 = wr4[256 + i];          // Wr row 1
        a0 = fmaf(v.x, w0.x, fmaf(v.y, w0.y, fmaf(v.z, w0.z, fmaf(v.w, w0.w, a0))));
        a1 = fmaf(v.x, w1.x, fmaf(v.y, w1.y, fmaf(v.z, w1.z, fmaf(v.w, w1.w, a1))));
        a2 = fmaf(v.x, w2.x, fmaf(v.y, w2.y, fmaf(v.z, w2.z, fmaf(v.w, w2.w, a2))));
        a3 = fmaf(v.x, w3.x, fmaf(v.y, w3.y, fmaf(v.z, w3.z, fmaf(v.w, w3.w, a3))));
    }
#pragma unroll
    for (int m = 1; m < 64; m <<= 1) {
        a0 += __shfl_xor(a0, m, 64);
        a1 += __shfl_xor(a1, m, 64);
        a2 += __shfl_xor(a2, m, 64);
        a3 += __shfl_xor(a3, m, 64);
    }
    if (lane == 0) {
        float l0 = a0 + bd[0], l1 = a1 + bd[1], l2 = a2 + bd[2];
        float mx = fmaxf(fmaxf(l0, l1), l2);
        float e0 = __expf(l0 - mx), e1 = __expf(l1 - mx), e2 = __expf(l2 - mx);
        float inv = 1.f / (e0 + e1 + e2);
        float r = 1.f / (1.f + __expf(-(a3 + br[1])));
        ((float4*)dtr)[wid] = make_float4(e0 * inv, e1 * inv, e2 * inv, r);
    }
}

// ---------- Phase 1b: evolve pos per batch; store pos_t (pre-update) for all t.
// one wave per b; pos[l] split: lane holds l=lane (p0) and l=lane+64 (p1).
// (shfl-based version — harness-verified R0-R8. DPP wave-rotate variant
// FAILED correctness in R9: rotation direction convention wrong. Do not
// retry without an isolated direction test.)
__global__ __launch_bounds__(64) void k_pos(const float* __restrict__ dtr,
                                            float* __restrict__ pos_all) {
    int b = blockIdx.x;
    int lane = threadIdx.x;
    const float4* dtr4 = (const float4*)dtr;
    float4 dreg[8];
#pragma unroll
    for (int k = 0; k < 8; k++)
        dreg[k] = dtr4[(((size_t)(k << 6) + lane) << 6) + b];   // t = k*64+lane
    float p0 = (lane == 0) ? 1.f : 0.f;
    float p1 = 0.f;
    float* outp = pos_all + ((size_t)b << 7) + lane;
    int up = (lane + 1) & 63, dw = (lane + 63) & 63;
#pragma unroll
    for (int k = 0; k < 8; k++) {
#pragma unroll 4
        for (int tt = 0; tt < 64; tt++) {
            int t = (k << 6) + tt;
            float d0 = __shfl(dreg[k].x, tt, 64);
            float d1 = __shfl(dreg[k].y, tt, 64);
            float d2 = __shfl(dreg[k].z, tt, 64);
            outp[(size_t)t * (B_ * T_)]      = p0;   // pos_t before update
            outp[(size_t)t * (B_ * T_) + 64] = p1;
            float s0n = __shfl(p0, up, 64), s1n = __shfl(p1, up, 64);
            float s0p = __shfl(p0, dw, 64), s1p = __shfl(p1, dw, 64);
            float up0 = (lane == 63) ? s1n : s0n;   // pos[(l+1)%128], l=lane
            float dn0 = (lane == 0)  ? s1p : s0p;   // pos[(l-1)%128]
            float up1 = (lane == 63) ? s0n : s1n;   // l=lane+64
            float dn1 = (lane == 0)  ? s0p : s1p;
            p0 = fmaf(up0, d0, fmaf(p0, d1, dn0 * d2));
            p1 = fmaf(up1, d0, fmaf(p1, d1, dn1 * d2));
        }
    }
}

// ---------- Phase 2: the scan (round-6 structure, frozen — empirical optimum
// across 5 structural variants). ALL streamed data (pos, v, rw) in LDS
// double-buffers; registers hold only tape + per-step temporaries. l-group
// reduce via DPP (no LDS pipe).
// Lanes: g = lane&7 (16 l's: [16g,16g+16)), cl = lane>>3 (4 c's).
// pos LDS: slot p(pi) = (pi&3)*8 + (pi>>2); step read [ts][j*8+g] j=0..3
// -> 8 consecutive float4 slots per instr, all 32 banks, broadcast x8.
// v LDS: [ts][32 float4] identity; rw: same-address broadcast.
// T14 staging: global->reg at chunk start, ds_write after compute, 1 barrier.
// Grid: 64 b x 8 cblk = 512 blocks = 2 blocks/CU = 2 waves/SIMD.
__global__ __launch_bounds__(256, 2) void k_scan(const float* __restrict__ values,
                                                 const float* __restrict__ dtr,
                                                 const float* __restrict__ pos_all,
                                                 float* __restrict__ tape_out) {
    const int b    = blockIdx.x >> 3;
    const int cblk = blockIdx.x & 7;
    const int tid  = threadIdx.x;
    const int lane = tid & 63;
    const int wv   = tid >> 6;            // wave in block, 0..3
    const int g    = lane & 7;            // l-group
    const int cl   = lane >> 3;           // c-slot in wave, 0..7
    const int c0   = (cblk << 7) + (wv << 5) + (cl << 2);   // 4 consecutive c

    __shared__ float4 pos_s[2][8][32];    // [buf][t][permuted float4 of 128 l]
    __shared__ float4 v_s[2][8][32];      // [buf][t][float4 of block's 128 c]
    __shared__ float  rw_s[2][8];

    float tape[16][4];
#pragma unroll
    for (int k = 0; k < 16; k++)
#pragma unroll
        for (int c = 0; c < 4; c++) tape[k][c] = 0.f;

    // staging roles: thread stages one float4 of pos and one of v per chunk
    const int tl   = tid >> 5;            // 0..7 (t within chunk)
    const int pi   = tid & 31;            // source float4 index
    const int pdst = ((pi & 3) << 3) + (pi >> 2);   // interleave permutation
    const float4* pos4 = (const float4*)pos_all;
    const float4* val4 = (const float4*)values;
    const size_t  vsrc = (size_t)b * (C_ / 4) + (cblk << 5) + pi;

    // ---- prologue: stage chunk 0
    {
        pos_s[0][tl][pdst] = pos4[((size_t)tl * B_ + b) * (T_ / 4) + pi];
        v_s[0][tl][pi]     = val4[(size_t)tl * (B_ * C_ / 4) + vsrc];
        if (tid < 8) rw_s[0][tid] = dtr[(((size_t)tid * B_ + b) << 2) + 3];
    }
    __syncthreads();

    int cur = 0;
    for (int ch = 0; ch < S_ / 8; ch++) {
        // ---- prefetch chunk ch+1 into regs (clamped re-read on last chunk)
        const int t0n = (ch + 1 < S_ / 8) ? ((ch + 1) << 3) : 0;
        float4 pfp = pos4[((size_t)(t0n + tl) * B_ + b) * (T_ / 4) + pi];
        float4 pfv = val4[(size_t)(t0n + tl) * (B_ * C_ / 4) + vsrc];
        float  pfr = (tid < 8) ? dtr[(((size_t)(t0n + tid) * B_ + b) << 2) + 3] : 0.f;

        // ---- compute 8 steps from buf cur
#pragma unroll
        for (int ts = 0; ts < 8; ts++) {
            float4 pj0 = pos_s[cur][ts][g];          // k 0..3   (l = 16g+k)
            float4 pj1 = pos_s[cur][ts][8 + g];      // k 4..7
            float4 pj2 = pos_s[cur][ts][16 + g];     // k 8..11
            float4 pj3 = pos_s[cur][ts][24 + g];     // k 12..15
            float4 vv  = v_s[cur][ts][(wv << 3) + cl];
            float  rw  = rw_s[cur][ts];
            float pk[16];
            pk[0]  = pj0.x; pk[1]  = pj0.y; pk[2]  = pj0.z; pk[3]  = pj0.w;
            pk[4]  = pj1.x; pk[5]  = pj1.y; pk[6]  = pj1.z; pk[7]  = pj1.w;
            pk[8]  = pj2.x; pk[9]  = pj2.y; pk[10] = pj2.z; pk[11] = pj2.w;
            pk[12] = pj3.x; pk[13] = pj3.y; pk[14] = pj3.z; pk[15] = pj3.w;

            float ov[4] = {0.f, 0.f, 0.f, 0.f};
#pragma unroll
            for (int k = 0; k < 16; k++) {
                ov[0] = fmaf(tape[k][0], pk[k], ov[0]);
                ov[1] = fmaf(tape[k][1], pk[k], ov[1]);
                ov[2] = fmaf(tape[k][2], pk[k], ov[2]);
                ov[3] = fmaf(tape[k][3], pk[k], ov[3]);
            }
            // DPP reduce over the 8 l-groups (lane bits 0..2), pure VALU
#pragma unroll
            for (int c = 0; c < 4; c++) {
                ov[c] = DPP_ADD(ov[c], 0xB1);    // += lane^1
                ov[c] = DPP_ADD(ov[c], 0x4E);    // += lane^2
                ov[c] = DPP_ADD(ov[c], 0x141);   // += lane^4 (half-mirror)
            }
            float de[4];
            de[0] = (vv.x - ov[0]) * rw;
            de[1] = (vv.y - ov[1]) * rw;
            de[2] = (vv.z - ov[2]) * rw;
            de[3] = (vv.w - ov[3]) * rw;
#pragma unroll
            for (int k = 0; k < 16; k++) {
                tape[k][0] = fmaf(pk[k], de[0], tape[k][0]);
                tape[k][1] = fmaf(pk[k], de[1], tape[k][1]);
                tape[k][2] = fmaf(pk[k], de[2], tape[k][2]);
                tape[k][3] = fmaf(pk[k], de[3], tape[k][3]);
            }
        }
        // ---- land prefetched chunk into the other buffer
        int nxt = cur ^ 1;
        pos_s[nxt][tl][pdst] = pfp;
        v_s[nxt][tl][pi]     = pfv;
        if (tid < 8) rw_s[nxt][tid] = pfr;
        __syncthreads();
        cur = nxt;
    }

    // writeout: layout [l][b][c]; this lane owns l = 16g + k, c = c0..c0+3
#pragma unroll
    for (int k = 0; k < 16; k++) {
        int l = (g << 4) + k;
        *(float4*)(tape_out + ((size_t)l * B_ + b) * C_ + c0) =
            make_float4(tape[k][0], tape[k][1], tape[k][2], tape[k][3]);
    }
}

// ---------- Phase 3: LayerNorm over C + projection to V=10. one wave per (l,b).
// float4-vectorized loads.
__global__ __launch_bounds__(256) void k_out(const float* __restrict__ tape,
                                             const float* __restrict__ ln_g,
                                             const float* __restrict__ ln_b,
                                             const float* __restrict__ Wo,
                                             const float* __restrict__ bo,
                                             float* __restrict__ out) {
    int wid  = (blockIdx.x << 2) + (threadIdx.x >> 6);   // 0..8191 = l*64+b
    int lane = threadIdx.x & 63;
    const float4* tr4 = (const float4*)(tape + (size_t)wid * C_);
    float4 x[4];
    float s = 0.f, s2 = 0.f;
#pragma unroll
    for (int j = 0; j < 4; j++) {
        x[j] = tr4[(j << 6) + lane];
        s += (x[j].x + x[j].y) + (x[j].z + x[j].w);
        s2 = fmaf(x[j].x, x[j].x, s2);
        s2 = fmaf(x[j].y, x[j].y, s2);
        s2 = fmaf(x[j].z, x[j].z, s2);
        s2 = fmaf(x[j].w, x[j].w, s2);
    }
#pragma unroll
    for (int m = 1; m < 64; m <<= 1) {
        s  += __shfl_xor(s,  m, 64);
        s2 += __shfl_xor(s2, m, 64);
    }
    float mu = s * (1.f / C_);
    float var = s2 * (1.f / C_) - mu * mu;
    float rstd = rsqrtf(var + LN_EPS);
    float acc[V_];
#pragma unroll
    for (int v = 0; v < V_; v++) acc[v] = 0.f;
    const float4* g4 = (const float4*)ln_g;
    const float4* b4 = (const float4*)ln_b;
    const float4* w4 = (const float4*)Wo;
#pragma unroll
    for (int j = 0; j < 4; j++) {
        int ci = (j << 6) + lane;          // float4 index within C/4
        float4 gg = g4[ci], bb = b4[ci];
        float4 h;
        h.x = fmaf((x[j].x - mu) * rstd, gg.x, bb.x);
        h.y = fmaf((x[j].y - mu) * rstd, gg.y, bb.y);
        h.z = fmaf((x[j].z - mu) * rstd, gg.z, bb.z);
        h.w = fmaf((x[j].w - mu) * rstd, gg.w, bb.w);
#pragma unroll
        for (int v = 0; v < V_; v++) {
            float4 w = w4[v * (C_ / 4) + ci];
            acc[v] = fmaf(h.x, w.x, acc[v]);
            acc[v] = fmaf(h.y, w.y, acc[v]);
            acc[v] = fmaf(h.z, w.z, acc[v]);
            acc[v] = fmaf(h.w, w.w, acc[v]);
        }
    }
#pragma unroll
    for (int v = 0; v < V_; v++) {
#pragma unroll
        for (int m = 1; m < 64; m <<= 1) acc[v] += __shfl_xor(acc[v], m, 64);
    }
    if (lane == 0) {
#pragma unroll
        for (int v = 0; v < V_; v++) out[(size_t)wid * V_ + v] = acc[v] + bo[v];
    }
}

extern "C" void kernel_launch(void* const* d_in, const int* in_sizes, int n_in,
                              void* d_out, int out_size, void* d_ws, size_t ws_size,
                              hipStream_t stream) {
    const float* values = (const float*)d_in[0];
    const float* Wd     = (const float*)d_in[1];
    const float* bd     = (const float*)d_in[2];
    const float* Wr     = (const float*)d_in[3];
    const float* br     = (const float*)d_in[4];
    const float* ln_g   = (const float*)d_in[5];
    const float* ln_b   = (const float*)d_in[6];
    const float* Wo     = (const float*)d_in[7];
    const float* bo     = (const float*)d_in[8];
    float* out = (float*)d_out;

    // workspace layout (floats): dtr [512*64*4] | pos_all [512*64*128] | tape [128*64*1024]
    float* dtr     = (float*)d_ws;
    float* pos_all = dtr + (size_t)S_ * B_ * 4;
    float* tape    = pos_all + (size_t)S_ * B_ * T_;

    k_dirs<<<dim3((S_ * B_) / 4), dim3(256), 0, stream>>>(values, Wd, bd, Wr, br, dtr);
    k_pos <<<dim3(B_),            dim3(64),  0, stream>>>(dtr, pos_all);
    k_scan<<<dim3(B_ * 8),        dim3(256), 0, stream>>>(values, dtr, pos_all, tape);
    k_out <<<dim3((T_ * B_) / 4), dim3(256), 0, stream>>>(tape, ln_g, ln_b, Wo, bo, out);
}